// Round 3
// baseline (229.457 us; speedup 1.0000x reference)
//
#include <hip/hip_runtime.h>

// CQT on gfx950 — all-MFMA pipeline.
//   Wr[b,n] = sum_k kr[b,k]*cos(2pi k n/2048) - ki[b,k]*sin(...)
//   Wi[b,n] = sum_k kr[b,k]*sin(...) + ki[b,k]*cos(...)
//   cqt[b,f] = sqrt( (sum_n x[512f+n]*W[2b,n])^2 + (sum_n x[512f+n]*W[2b+1,n])^2 )
// K1 aprep: build A'[192][2112] bf16: row 2b = [kr_b | -ki_b], row 2b+1 = [ki_b | kr_b]
//           (cos block k=0..1024, sin block k=1025..2049, zero pad to 2112).
// K2 wgemm: Wp[192][2048] = A' @ [wcos; wsin] (B staged+transposed from the f32
//           tables, coalesced row-major reads). fp32 accum, bf16 out.
// K3 cqt:   C[192,16381] = Wp @ B, B[k,f]=x[512f+k]. 8 waves/block (2/SIMD),
//           dbuf LDS, 1 barrier/iter, all-b128 LDS traffic.

#define HOPS 512
#define NBINS 84
#define FREQB 1025
#define FFTLEN 2048
#define NFRAMES 16381
#define MROWS 192
#define KPAD 2112
#define SINBASE 1025
#define KCHUNKS 33

typedef short bf16x8 __attribute__((ext_vector_type(8)));
typedef float f32x4 __attribute__((ext_vector_type(4)));

__device__ __forceinline__ unsigned short f32_to_bf16(float f) {
    union { float f; unsigned u; } v; v.f = f;
    return (unsigned short)((v.u + 0x7FFFu + ((v.u >> 16) & 1u)) >> 16);
}
__device__ __forceinline__ unsigned pk_bf16(float lo, float hi) {
    return (unsigned)f32_to_bf16(lo) | ((unsigned)f32_to_bf16(hi) << 16);
}

// ---------------- Kernel 1: A' prep ----------------
// grid 192 x 256. Row r: b=r>>1, im=r&1. A'[r][k] per layout above.
__global__ __launch_bounds__(256) void aprep_kernel(
    const float* __restrict__ kr, const float* __restrict__ ki,
    unsigned short* __restrict__ Ap)
{
    const int r = blockIdx.x;
    const int b = r >> 1, im = r & 1;
    #pragma unroll
    for (int p = 0; p < 9; ++p) {
        int k = threadIdx.x + p * 256;
        if (k < KPAD) {
            float v = 0.f;
            if (b < NBINS) {
                if (k <= 1024)
                    v = im ? ki[b * FREQB + k] : kr[b * FREQB + k];
                else if (k <= 2049) {
                    int kk = k - SINBASE;
                    v = im ? kr[b * FREQB + kk] : -ki[b * FREQB + kk];
                }
            }
            Ap[r * KPAD + k] = f32_to_bf16(v);
        }
    }
}

// ---------------- Kernel 2: W GEMM ----------------
// grid 32 x 512 (8 waves). Block: 192 rows x 64 n-cols, K=2112 (33 chunks).
// B tile [n][k] staged transposed from wcos/wsin f32 (coalesced n-major reads).
__global__ __launch_bounds__(512) void wgemm_kernel(
    const float* __restrict__ wcos, const float* __restrict__ wsin,
    const unsigned short* __restrict__ Ap, unsigned short* __restrict__ Wp)
{
    __shared__ __align__(16) unsigned short Al[MROWS * 72];
    __shared__ __align__(16) unsigned short Bl[64 * 72];

    const int t = threadIdx.x;
    const int n0 = blockIdx.x * 64;
    const int w = t >> 6, l = t & 63;
    const int mg = w >> 1, fg = w & 1;
    const int q = l >> 4, col = l & 15;

    f32x4 acc[3][2];
    #pragma unroll
    for (int mt = 0; mt < 3; ++mt)
        #pragma unroll
        for (int nt = 0; nt < 2; ++nt)
            acc[mt][nt] = (f32x4){0.f, 0.f, 0.f, 0.f};

    for (int c = 0; c < KCHUNKS; ++c) {
        const int k0 = c * 64;
        // stage A: 192x64 bf16, pure copy
        #pragma unroll
        for (int p = 0; p < 3; ++p) {
            int e = t + p * 512;
            int row = e >> 3, oct = e & 7;
            *(uint4*)(Al + row * 72 + oct * 8) =
                *(const uint4*)(Ap + row * KPAD + k0 + oct * 8);
        }
        // stage B transposed: thread owns k = t>>3, n-span (t&7)*8..+7
        {
            int k = t >> 3, ng = t & 7;
            int kg = k0 + k;
            float4 a = make_float4(0.f, 0.f, 0.f, 0.f), b = a;
            if (kg <= 2049) {
                const float* src = (kg <= 1024) ? (wcos + (size_t)kg * FFTLEN)
                                                : (wsin + (size_t)(kg - SINBASE) * FFTLEN);
                a = *(const float4*)(src + n0 + ng * 8);
                b = *(const float4*)(src + n0 + ng * 8 + 4);
            }
            int nb = ng * 8;
            Bl[(nb + 0) * 72 + k] = f32_to_bf16(a.x);
            Bl[(nb + 1) * 72 + k] = f32_to_bf16(a.y);
            Bl[(nb + 2) * 72 + k] = f32_to_bf16(a.z);
            Bl[(nb + 3) * 72 + k] = f32_to_bf16(a.w);
            Bl[(nb + 4) * 72 + k] = f32_to_bf16(b.x);
            Bl[(nb + 5) * 72 + k] = f32_to_bf16(b.y);
            Bl[(nb + 6) * 72 + k] = f32_to_bf16(b.z);
            Bl[(nb + 7) * 72 + k] = f32_to_bf16(b.w);
        }
        __syncthreads();

        #pragma unroll
        for (int ks = 0; ks < 2; ++ks) {
            bf16x8 bfrag[2], afrag[3];
            #pragma unroll
            for (int nt = 0; nt < 2; ++nt)
                bfrag[nt] = *(const bf16x8*)(Bl + (fg * 32 + nt * 16 + col) * 72 + ks * 32 + q * 8);
            #pragma unroll
            for (int mt = 0; mt < 3; ++mt)
                afrag[mt] = *(const bf16x8*)(Al + (mg * 48 + mt * 16 + col) * 72 + ks * 32 + q * 8);
            #pragma unroll
            for (int mt = 0; mt < 3; ++mt)
                #pragma unroll
                for (int nt = 0; nt < 2; ++nt)
                    acc[mt][nt] = __builtin_amdgcn_mfma_f32_16x16x32_bf16(
                        afrag[mt], bfrag[nt], acc[mt][nt], 0, 0, 0);
        }
        __syncthreads();
    }

    // epilogue: C row = mg*48+mt*16+4q+reg, col n = n0+fg*32+nt*16+col
    #pragma unroll
    for (int mt = 0; mt < 3; ++mt) {
        int rb = mg * 48 + mt * 16 + 4 * q;
        #pragma unroll
        for (int nt = 0; nt < 2; ++nt) {
            int n = n0 + fg * 32 + nt * 16 + col;
            f32x4 a = acc[mt][nt];
            Wp[(rb + 0) * FFTLEN + n] = f32_to_bf16(a.x);
            Wp[(rb + 1) * FFTLEN + n] = f32_to_bf16(a.y);
            Wp[(rb + 2) * FFTLEN + n] = f32_to_bf16(a.z);
            Wp[(rb + 3) * FFTLEN + n] = f32_to_bf16(a.w);
        }
    }
}

// ---------------- Kernel 3: main GEMM ----------------
// grid 256 x 512 (8 waves = 2/SIMD). Block 192 rows x 64 frames, BK=64, dbuf,
// 1 barrier/iter. Wave: mg(48 rows, mt=3) x fg(32 f, nt=2). All-b128 LDS ops.
__global__ __launch_bounds__(512) void cqt_kernel(
    const float* __restrict__ x, const unsigned short* __restrict__ Wp,
    float* __restrict__ out)
{
    __shared__ __align__(16) unsigned short Al[2][MROWS * 72];
    __shared__ __align__(16) unsigned short Bl[2][64 * 72];

    const int t = threadIdx.x;
    const int f0 = blockIdx.x * 64;
    const int w = t >> 6, l = t & 63;
    const int mg = w >> 1, fg = w & 1;
    const int q = l >> 4, col = l & 15;

    f32x4 acc[3][2];
    #pragma unroll
    for (int mt = 0; mt < 3; ++mt)
        #pragma unroll
        for (int nt = 0; nt < 2; ++nt)
            acc[mt][nt] = (f32x4){0.f, 0.f, 0.f, 0.f};

    uint4 aR[3];
    float4 bR0, bR1;
    const int sf = t >> 3, soct = t & 7;       // B-staging coords
    const int sfi = f0 + sf;

    auto load_chunk = [&](int kidx) {
        int k0 = kidx * 64;
        #pragma unroll
        for (int p = 0; p < 3; ++p) {
            int e = t + p * 512;
            int row = e >> 3, oct = e & 7;
            aR[p] = *(const uint4*)(Wp + row * FFTLEN + k0 + oct * 8);
        }
        if (sfi < NFRAMES) {
            bR0 = *(const float4*)(x + sfi * HOPS + k0 + soct * 8);
            bR1 = *(const float4*)(x + sfi * HOPS + k0 + soct * 8 + 4);
        } else {
            bR0 = make_float4(0.f, 0.f, 0.f, 0.f);
            bR1 = bR0;
        }
    };
    auto write_lds = [&](int buf) {
        #pragma unroll
        for (int p = 0; p < 3; ++p) {
            int e = t + p * 512;
            int row = e >> 3, oct = e & 7;
            *(uint4*)(&Al[buf][row * 72 + oct * 8]) = aR[p];
        }
        uint4 u;
        u.x = pk_bf16(bR0.x, bR0.y);
        u.y = pk_bf16(bR0.z, bR0.w);
        u.z = pk_bf16(bR1.x, bR1.y);
        u.w = pk_bf16(bR1.z, bR1.w);
        *(uint4*)(&Bl[buf][sf * 72 + soct * 8]) = u;
    };
    auto compute = [&](int buf) {
        #pragma unroll
        for (int ks = 0; ks < 2; ++ks) {
            bf16x8 bfrag[2], afrag[3];
            #pragma unroll
            for (int nt = 0; nt < 2; ++nt)
                bfrag[nt] = *(const bf16x8*)(&Bl[buf][(fg * 32 + nt * 16 + col) * 72 + ks * 32 + q * 8]);
            #pragma unroll
            for (int mt = 0; mt < 3; ++mt)
                afrag[mt] = *(const bf16x8*)(&Al[buf][(mg * 48 + mt * 16 + col) * 72 + ks * 32 + q * 8]);
            #pragma unroll
            for (int mt = 0; mt < 3; ++mt)
                #pragma unroll
                for (int nt = 0; nt < 2; ++nt)
                    acc[mt][nt] = __builtin_amdgcn_mfma_f32_16x16x32_bf16(
                        afrag[mt], bfrag[nt], acc[mt][nt], 0, 0, 0);
        }
    };

    load_chunk(0);
    write_lds(0);
    __syncthreads();
    load_chunk(1);

    for (int it = 0; it < 32; ++it) {
        compute(it & 1);
        if (it < 31) {
            write_lds((it + 1) & 1);
            if (it < 30) load_chunk(it + 2);
            __syncthreads();
        }
    }

    // epilogue: row = mg*48+mt*16+4q (even); bins b0=row/2 (regs x,y), b0+1 (z,w)
    #pragma unroll
    for (int mt = 0; mt < 3; ++mt) {
        int rb = mg * 48 + mt * 16 + 4 * q;
        int b0 = rb >> 1;
        #pragma unroll
        for (int nt = 0; nt < 2; ++nt) {
            int f = f0 + fg * 32 + nt * 16 + col;
            if (f < NFRAMES) {
                f32x4 a = acc[mt][nt];
                if (b0 < NBINS)
                    out[b0 * NFRAMES + f] = sqrtf(a.x * a.x + a.y * a.y);
                if (b0 + 1 < NBINS)
                    out[(b0 + 1) * NFRAMES + f] = sqrtf(a.z * a.z + a.w * a.w);
            }
        }
    }
}

extern "C" void kernel_launch(void* const* d_in, const int* in_sizes, int n_in,
                              void* d_out, int out_size, void* d_ws, size_t ws_size,
                              hipStream_t stream) {
    const float* x    = (const float*)d_in[0];
    const float* wcos = (const float*)d_in[1];
    const float* wsin = (const float*)d_in[2];
    const float* kr   = (const float*)d_in[3];
    const float* ki   = (const float*)d_in[4];
    float* out = (float*)d_out;

    unsigned short* Wp = (unsigned short*)d_ws;                    // 786,432 B
    unsigned short* Ap = (unsigned short*)((char*)d_ws + 786432);  // 811,008 B

    aprep_kernel<<<dim3(192), dim3(256), 0, stream>>>(kr, ki, Ap);
    wgemm_kernel<<<dim3(32), dim3(512), 0, stream>>>(wcos, wsin, Ap, Wp);
    cqt_kernel<<<dim3(256), dim3(512), 0, stream>>>(x, Wp, out);
}